// Round 4
// baseline (321.232 us; speedup 1.0000x reference)
//
#include <hip/hip_runtime.h>
#include <math.h>

#define NHID 1024
#define NPC  225
#define NCLS 224
#define BATCH 1024
#define NBLK  256               // exactly 1 block per CU

typedef float f4u __attribute__((ext_vector_type(4), aligned(4)));

// ws float-offsets
#define WS_PT 0                 // float pt[1024]
#define WS_PB 1024              // float pb[1024]

// ---------------------------------------------------------------------------
// Single fused kernel, 256 blocks x 1024 threads (16 waves), 1 block/CU.
// Every block: (a) self-groups (hist + scan over labels, ~2us, parallel),
// (b) processes bottom item(s) item = bid, bid+256, ... (<=8 samples of one
// class; Wb slice streamed with float4 nontemporal loads), (c) processes top
// quarter-group bid (4 samples) -- top work is spread over ALL 256 blocks so
// it hides under the bottom HBM stream with no straggler tail.
// (Resubmission of round-3 source: container-level failure, no kernel defect
// found on audit.)
// ---------------------------------------------------------------------------
__global__ __launch_bounds__(1024, 4) void k_fused(const float* __restrict__ X,
                                                   const int* __restrict__ labels,
                                                   const float* __restrict__ Wt,
                                                   const float* __restrict__ bt,
                                                   const float* __restrict__ Wb,
                                                   const float* __restrict__ bb,
                                                   float* __restrict__ ws)
{
    __shared__ __align__(16) float sm[15360]; // staging / red[64][240] (61.4KB)
    __shared__ int cnt_[256];
    __shared__ int iscan_[256];
    __shared__ int slot[8];
    __shared__ int wtot[16];

    const int tid  = threadIdx.x;
    const int wave = tid >> 6;
    const int lane = tid & 63;
    const int j8   = tid & 7;
    const int t8   = tid >> 3;
    const int bid  = blockIdx.x;

    // ---- self-grouping: histogram + inclusive scan of item counts ----
    if (tid < 256) cnt_[tid] = 0;
    __syncthreads();
    const int myc = labels[tid] / NPC;          // tid < 1024 == BATCH
    atomicAdd(&cnt_[myc], 1);
    __syncthreads();
    if (tid < 256) iscan_[tid] = (tid < NCLS) ? ((cnt_[tid] + 7) >> 3) : 0;
    __syncthreads();
    for (int off = 1; off < 256; off <<= 1) {
        int a = 0;
        if (tid < 256 && tid >= off) a = iscan_[tid - off];
        __syncthreads();
        if (tid < 256 && tid >= off) iscan_[tid] += a;
        __syncthreads();
    }
    const int nitems = iscan_[255];

    // ------------------------- bottom items -------------------------
    for (int item = bid; item < nitems; item += NBLK) {
        // locate class: first cls with iscan_[cls] > item (broadcast reads)
        int lo = 0, hi = NCLS - 1;
        while (lo < hi) {
            const int mid = (lo + hi) >> 1;
            if (iscan_[mid] > item) hi = mid; else lo = mid + 1;
        }
        const int cls    = lo;
        const int ibase  = (cls == 0) ? 0 : iscan_[cls - 1];
        const int within = item - ibase;
        const int nt     = min(8, cnt_[cls] - 8 * within);

        // deterministic compaction: ballot order == sample-index order
        {
            const bool flag = (myc == cls);
            const unsigned long long mb = __ballot(flag);
            if (lane == 0) wtot[wave] = __popcll(mb);
            __syncthreads();
            if (flag) {
                int pos = __popcll(mb & ((1ull << lane) - 1));
#pragma unroll
                for (int w = 0; w < 16; ++w)
                    if (w < wave) pos += wtot[w];
                const int r = pos - 8 * within;
                if (r >= 0 && r < 8) slot[r] = tid;
            }
            __syncthreads();
        }

        // stage nt rows of X transposed ([d][j], stride 12)
        const int sid = (j8 < nt) ? slot[j8] : -1;
        for (int d4 = t8; d4 < 256; d4 += 128) {
            float4 v = make_float4(0.f, 0.f, 0.f, 0.f);
            if (sid >= 0) v = ((const float4*)&X[(size_t)sid * NHID])[d4];
            float* p = &sm[48 * d4 + j8];
            p[0] = v.x; p[12] = v.y; p[24] = v.z; p[36] = v.w;
        }
        __syncthreads();

        float acc[8][4];
#pragma unroll
        for (int j = 0; j < 8; ++j)
#pragma unroll
            for (int k = 0; k < 4; ++k) acc[j][k] = 0.f;

        const int d0 = wave * 64;
        const float* Wr = Wb + (size_t)cls * (NHID * NPC) + (size_t)d0 * NPC;

        // lane l owns cols 4l..4l+3 (l<56); lane 56 owns col 224 (scalar,
        // avoids 12B overrun at the very end of Wb); lanes 57..63 idle.
        f4u wbuf[4];
        auto ldrow = [&](int r, f4u& o) {
            const float* p = Wr + (size_t)r * NPC;
            f4u t = {0.f, 0.f, 0.f, 0.f};
            if (lane < 56)       t = __builtin_nontemporal_load((const f4u*)(p + 4 * lane));
            else if (lane == 56) t.x = __builtin_nontemporal_load(p + 224);
            o = t;
        };
        ldrow(0, wbuf[0]); ldrow(1, wbuf[1]); ldrow(2, wbuf[2]); ldrow(3, wbuf[3]);

#pragma unroll 4
        for (int dd = 0; dd < 64; ++dd) {
            const int sl = dd & 3;
            const f4u cw = wbuf[sl];
            ldrow(min(dd + 4, 63), wbuf[sl]);   // clamped tail re-read
            const float4 a = *(const float4*)&sm[(d0 + dd) * 12 + 0];
            const float4 b = *(const float4*)&sm[(d0 + dd) * 12 + 4];
            const float xi[8] = {a.x, a.y, a.z, a.w, b.x, b.y, b.z, b.w};
#pragma unroll
            for (int j = 0; j < 8; ++j) {
                acc[j][0] = fmaf(xi[j], cw.x, acc[j][0]);
                acc[j][1] = fmaf(xi[j], cw.y, acc[j][1]);
                acc[j][2] = fmaf(xi[j], cw.z, acc[j][2]);
                acc[j][3] = fmaf(xi[j], cw.w, acc[j][3]);
            }
        }
        __syncthreads();   // all waves done reading staging

        float* red = sm;   // red[(g*8+j)*240 + 4*lane + k], float4-wide
        if (wave >= 8 && lane <= 56) {
#pragma unroll
            for (int j = 0; j < 8; ++j)
                *(float4*)&red[((wave - 8) * 8 + j) * 240 + 4 * lane] =
                    make_float4(acc[j][0], acc[j][1], acc[j][2], acc[j][3]);
        }
        __syncthreads();
        if (wave < 8 && lane <= 56) {
#pragma unroll
            for (int j = 0; j < 8; ++j) {
                float4* q = (float4*)&red[(wave * 8 + j) * 240 + 4 * lane];
                float4 t = *q;
                t.x += acc[j][0]; t.y += acc[j][1];
                t.z += acc[j][2]; t.w += acc[j][3];
                *q = t;
            }
        }
        __syncthreads();

        if (wave < 8 && wave < nt) {
            const int j = wave;
            const int s = slot[j];
            const int cb = 4 * lane;
            float v0 = -INFINITY, v1 = -INFINITY, v2 = -INFINITY, v3 = -INFINITY;
            if (lane <= 56) {
                float t0 = bb[(size_t)cls * NPC + cb];
                float t1 = (cb + 1 < NPC) ? bb[(size_t)cls * NPC + cb + 1] : 0.f;
                float t2 = (cb + 2 < NPC) ? bb[(size_t)cls * NPC + cb + 2] : 0.f;
                float t3 = (cb + 3 < NPC) ? bb[(size_t)cls * NPC + cb + 3] : 0.f;
#pragma unroll
                for (int g = 0; g < 8; ++g) {
                    const float4 rg = *(const float4*)&red[(g * 8 + j) * 240 + cb];
                    t0 += rg.x; t1 += rg.y; t2 += rg.z; t3 += rg.w;
                }
                v0 = t0;
                v1 = (cb + 1 < NPC) ? t1 : -INFINITY;
                v2 = (cb + 2 < NPC) ? t2 : -INFINITY;
                v3 = (cb + 3 < NPC) ? t3 : -INFINITY;
            }
            float m = fmaxf(fmaxf(v0, v1), fmaxf(v2, v3));
            for (int o = 32; o > 0; o >>= 1) m = fmaxf(m, __shfl_xor(m, o));
            float e = expf(v0 - m) + expf(v1 - m) + expf(v2 - m) + expf(v3 - m);
            for (int o = 32; o > 0; o >>= 1) e += __shfl_xor(e, o);
            const int pb = labels[s] % NPC;
            if (lane == (pb >> 2)) {
                const int kk = pb & 3;
                const float vs = kk == 0 ? v0 : kk == 1 ? v1 : kk == 2 ? v2 : v3;
                ws[WS_PB + s] = expf(vs - m) / e;
            }
        }
        __syncthreads();   // before next item / top phase reuses sm
    }

    // ------------------- top quarter-group (4 samples) -------------------
    __syncthreads();
    const int sbase = bid * 4;
    {
        const int j4 = tid & 3;
        const int d4 = tid >> 2;            // 0..255, one float4 per thread
        const float4 xv = ((const float4*)&X[(size_t)(sbase + j4) * NHID])[d4];
        float* p = &sm[16 * d4 + j4];       // sm[4*d + j]
        p[0] = xv.x; p[4] = xv.y; p[8] = xv.z; p[12] = xv.w;
    }
    __syncthreads();

    float acc[4][4];
#pragma unroll
    for (int j = 0; j < 4; ++j)
#pragma unroll
        for (int k = 0; k < 4; ++k) acc[j][k] = 0.f;

    const int c0 = lane, c1 = lane + 64, c2 = lane + 128, c3 = lane + 192;
    const bool m3 = (c3 < NCLS);
    const int d0 = wave * 64;
    const float* Wr = Wt + (size_t)d0 * NCLS;

    auto ldrowT = [&](int r, float* o) {
        const float* p = Wr + (size_t)r * NCLS;
        o[0] = p[c0]; o[1] = p[c1]; o[2] = p[c2];
        o[3] = m3 ? p[c3] : 0.f;
    };
    float wb[4][4];
    ldrowT(0, wb[0]); ldrowT(1, wb[1]); ldrowT(2, wb[2]); ldrowT(3, wb[3]);

#pragma unroll 4
    for (int dd = 0; dd < 64; ++dd) {
        const int sl = dd & 3;
        const float cw0 = wb[sl][0], cw1 = wb[sl][1],
                    cw2 = wb[sl][2], cw3 = wb[sl][3];
        ldrowT(min(dd + 4, 63), wb[sl]);
        const float4 a = *(const float4*)&sm[4 * (d0 + dd)];
        const float xi[4] = {a.x, a.y, a.z, a.w};
#pragma unroll
        for (int j = 0; j < 4; ++j) {
            acc[j][0] = fmaf(xi[j], cw0, acc[j][0]);
            acc[j][1] = fmaf(xi[j], cw1, acc[j][1]);
            acc[j][2] = fmaf(xi[j], cw2, acc[j][2]);
            acc[j][3] = fmaf(xi[j], cw3, acc[j][3]);
        }
    }
    __syncthreads();

    float* red = sm;   // red[(g*4+j)*232 + c], numerics identical to baseline
    if (wave >= 8) {
#pragma unroll
        for (int j = 0; j < 4; ++j)
#pragma unroll
            for (int k = 0; k < 4; ++k) {
                const int c = lane + 64 * k;
                if (c < NCLS) red[((wave - 8) * 4 + j) * 232 + c] = acc[j][k];
            }
    }
    __syncthreads();
    if (wave < 8) {
#pragma unroll
        for (int j = 0; j < 4; ++j)
#pragma unroll
            for (int k = 0; k < 4; ++k) {
                const int c = lane + 64 * k;
                if (c < NCLS) red[(wave * 4 + j) * 232 + c] += acc[j][k];
            }
    }
    __syncthreads();

    if (wave < 4) {
        const int j = wave;
        const int s = sbase + j;
        float v0, v1, v2, v3;
        {
            float vv[4];
#pragma unroll
            for (int k = 0; k < 4; ++k) {
                const int c = lane + 64 * k;
                if (c < NCLS) {
                    float t = bt[c];
#pragma unroll
                    for (int g = 0; g < 8; ++g) t += red[(g * 4 + j) * 232 + c];
                    vv[k] = t;
                } else vv[k] = -INFINITY;
            }
            v0 = vv[0]; v1 = vv[1]; v2 = vv[2]; v3 = vv[3];
        }
        float m = fmaxf(fmaxf(v0, v1), fmaxf(v2, v3));
        for (int o = 32; o > 0; o >>= 1) m = fmaxf(m, __shfl_xor(m, o));
        float e = expf(v0 - m) + expf(v1 - m) + expf(v2 - m) + expf(v3 - m);
        for (int o = 32; o > 0; o >>= 1) e += __shfl_xor(e, o);
        const int pt = labels[s] / NPC;
        if (lane == (pt & 63)) {
            const int kk = pt >> 6;
            const float vs = kk == 0 ? v0 : kk == 1 ? v1 : kk == 2 ? v2 : v3;
            ws[WS_PT + s] = expf(vs - m) / e;
        }
    }
}

// ---------------------------------------------------------------------------
// Finalize: out[s] = pt[s] * pb[s]
// ---------------------------------------------------------------------------
__global__ void k_mul(const float* __restrict__ ws, float* __restrict__ out)
{
    const int i = blockIdx.x * 256 + threadIdx.x;
    if (i < BATCH) out[i] = ws[WS_PT + i] * ws[WS_PB + i];
}

// ---------------------------------------------------------------------------
extern "C" void kernel_launch(void* const* d_in, const int* in_sizes, int n_in,
                              void* d_out, int out_size, void* d_ws, size_t ws_size,
                              hipStream_t stream)
{
    const float* X      = (const float*)d_in[0];
    const int*   labels = (const int*)  d_in[1];
    const float* Wt     = (const float*)d_in[2];
    const float* bt     = (const float*)d_in[3];
    const float* Wb     = (const float*)d_in[4];
    const float* bb     = (const float*)d_in[5];

    hipLaunchKernelGGL(k_fused, dim3(NBLK), dim3(1024), 0, stream,
                       X, labels, Wt, bt, Wb, bb, (float*)d_ws);
    hipLaunchKernelGGL(k_mul, dim3(BATCH / 256), dim3(256), 0, stream,
                       (const float*)d_ws, (float*)d_out);
}

// Round 5
// 295.753 us; speedup vs baseline: 1.0861x; 1.0861x over previous
//
#include <hip/hip_runtime.h>
#include <math.h>

#define NHID 1024
#define NPC  225
#define NCLS 224
#define BATCH 1024
#define N_TOPB 128              // top blocks: 8 samples each
#define N_BOTB 352              // max bottom items: sum ceil(cnt/8) <= 324

// ws float-offsets
#define WS_PT 0                 // float pt[1024]
#define WS_PB 1024              // float pb[1024]

// ---------------------------------------------------------------------------
// Shared panel routine: 8 staged samples vs one [NHID x ncols] weight panel,
// per-sample softmax over ncols, write the picked probability.
// 512 threads = 8 waves; wave w covers d-rows [128w, 128w+128).
// Scalar coalesced weight loads (64 consecutive cols per instruction).
// ---------------------------------------------------------------------------
template<bool NT>
__device__ __forceinline__ void panel8(const float* __restrict__ X,
                                       const int* __restrict__ labels,
                                       float* sm, const int* slot,
                                       const float* __restrict__ W, int ncols,
                                       const float* __restrict__ bias,
                                       int nt, bool use_mod,
                                       float* __restrict__ outp)
{
    const int tid  = threadIdx.x;
    const int wave = tid >> 6;
    const int lane = tid & 63;
    const int j8   = tid & 7;

    // stage nt rows of X transposed ([d][j], row stride 12)
    const int sid = (j8 < nt) ? slot[j8] : -1;
    for (int idx = tid; idx < 2048; idx += 512) {
        const int d4 = idx >> 3;
        float4 v = make_float4(0.f, 0.f, 0.f, 0.f);
        if (sid >= 0) v = ((const float4*)&X[(size_t)sid * NHID])[d4];
        float* p = &sm[48 * d4 + j8];
        p[0] = v.x; p[12] = v.y; p[24] = v.z; p[36] = v.w;
    }
    __syncthreads();

    float acc[8][4];
#pragma unroll
    for (int j = 0; j < 8; ++j)
#pragma unroll
        for (int k = 0; k < 4; ++k) acc[j][k] = 0.f;

    const int c0 = lane, c1 = lane + 64, c2 = lane + 128, c3 = lane + 192;
    const bool m3 = (c3 < ncols);
    const int d0 = wave * 128;
    const float* Wr = W + (size_t)d0 * ncols;

    auto ldrow = [&](int r, float* o) {
        const float* p = Wr + (size_t)r * ncols;
        if (NT) {
            o[0] = __builtin_nontemporal_load(p + c0);
            o[1] = __builtin_nontemporal_load(p + c1);
            o[2] = __builtin_nontemporal_load(p + c2);
            o[3] = m3 ? __builtin_nontemporal_load(p + c3) : 0.f;
        } else {
            o[0] = p[c0]; o[1] = p[c1]; o[2] = p[c2];
            o[3] = m3 ? p[c3] : 0.f;
        }
    };
    float wbuf[4][4];
    ldrow(0, wbuf[0]); ldrow(1, wbuf[1]); ldrow(2, wbuf[2]); ldrow(3, wbuf[3]);

#pragma unroll 4
    for (int dd = 0; dd < 128; ++dd) {
        const int sl = dd & 3;
        const float cw0 = wbuf[sl][0], cw1 = wbuf[sl][1],
                    cw2 = wbuf[sl][2], cw3 = wbuf[sl][3];
        ldrow(min(dd + 4, 127), wbuf[sl]);   // clamped tail re-read (cache hit)
        const float4 a = *(const float4*)&sm[(d0 + dd) * 12 + 0];
        const float4 b = *(const float4*)&sm[(d0 + dd) * 12 + 4];
        const float xi[8] = {a.x, a.y, a.z, a.w, b.x, b.y, b.z, b.w};
#pragma unroll
        for (int j = 0; j < 8; ++j) {
            acc[j][0] = fmaf(xi[j], cw0, acc[j][0]);
            acc[j][1] = fmaf(xi[j], cw1, acc[j][1]);
            acc[j][2] = fmaf(xi[j], cw2, acc[j][2]);
            acc[j][3] = fmaf(xi[j], cw3, acc[j][3]);
        }
    }
    __syncthreads();   // all waves done reading staging

    float* red = sm;   // red[(w*8 + j)*232 + c]
#pragma unroll
    for (int j = 0; j < 8; ++j)
#pragma unroll
        for (int k = 0; k < 4; ++k) {
            const int c = lane + 64 * k;
            if (c < ncols) red[(wave * 8 + j) * 232 + c] = acc[j][k];
        }
    __syncthreads();

    if (wave < nt) {
        const int j = wave;
        const int s = slot[j];
        float v0, v1, v2, v3;
        {
            float vv[4];
#pragma unroll
            for (int k = 0; k < 4; ++k) {
                const int c = lane + 64 * k;
                if (c < ncols) {
                    float t = bias[c];
#pragma unroll
                    for (int g = 0; g < 8; ++g) t += red[(g * 8 + j) * 232 + c];
                    vv[k] = t;
                } else vv[k] = -INFINITY;
            }
            v0 = vv[0]; v1 = vv[1]; v2 = vv[2]; v3 = vv[3];
        }
        float m = fmaxf(fmaxf(v0, v1), fmaxf(v2, v3));
        for (int o = 32; o > 0; o >>= 1) m = fmaxf(m, __shfl_xor(m, o));
        float e = expf(v0 - m) + expf(v1 - m) + expf(v2 - m) + expf(v3 - m);
        for (int o = 32; o > 0; o >>= 1) e += __shfl_xor(e, o);
        const int lab  = labels[s];
        const int pick = use_mod ? (lab % NPC) : (lab / NPC);
        if (lane == (pick & 63)) {
            const int kk = pick >> 6;
            const float vs = kk == 0 ? v0 : kk == 1 ? v1 : kk == 2 ? v2 : v3;
            outp[s] = expf(vs - m) / e;
        }
    }
}

// ---------------------------------------------------------------------------
// Fused kernel: 480 blocks x 512 threads (8 waves), 61.5 KB LDS, <=128 VGPR
// -> 2 blocks/CU co-resident; ALL 480 blocks resident from t=0, so top-block
// VALU work runs under the bottom blocks' HBM stream via CU-level overlap.
// Blocks 0..127: top softmax (8 samples each). Blocks 128..479: one bottom
// item each (<=8 samples of one class), self-grouped.
// ---------------------------------------------------------------------------
__global__ __launch_bounds__(512, 4) void k_fused(const float* __restrict__ X,
                                                  const int* __restrict__ labels,
                                                  const float* __restrict__ Wt,
                                                  const float* __restrict__ bt,
                                                  const float* __restrict__ Wb,
                                                  const float* __restrict__ bb,
                                                  float* __restrict__ ws)
{
    __shared__ __align__(16) float sm[14848]; // staging [256][48] / red[64][232]
    __shared__ int cnt_[256];
    __shared__ int iscan_[256];
    __shared__ int slot[8];
    __shared__ int wtA[8], wtB[8];

    const int tid  = threadIdx.x;
    const int wave = tid >> 6;
    const int lane = tid & 63;
    const int bid  = blockIdx.x;

    if (bid < N_TOPB) {
        // ----------------------------- top -----------------------------
        if (tid < 8) slot[tid] = bid * 8 + tid;
        __syncthreads();
        panel8<false>(X, labels, sm, slot, Wt, NCLS, bt, 8, false, ws + WS_PT);
        return;
    }

    // ---------------------------- bottom ----------------------------
    // self-grouping: histogram + inclusive scan of per-class item counts
    if (tid < 256) cnt_[tid] = 0;
    __syncthreads();
    const int la = labels[tid] / NPC;          // samples tid and tid+512
    const int lb = labels[tid + 512] / NPC;
    atomicAdd(&cnt_[la], 1);
    atomicAdd(&cnt_[lb], 1);
    __syncthreads();
    if (tid < 256) iscan_[tid] = (tid < NCLS) ? ((cnt_[tid] + 7) >> 3) : 0;
    __syncthreads();
    for (int off = 1; off < 256; off <<= 1) {
        int a = 0;
        if (tid < 256 && tid >= off) a = iscan_[tid - off];
        __syncthreads();
        if (tid < 256 && tid >= off) iscan_[tid] += a;
        __syncthreads();
    }
    const int item = bid - N_TOPB;
    if (item >= iscan_[255]) return;           // beyond nitems: uniform exit

    // locate class: first cls with iscan_[cls] > item (LDS broadcast reads)
    int lo = 0, hi = NCLS - 1;
    while (lo < hi) {
        const int mid = (lo + hi) >> 1;
        if (iscan_[mid] > item) hi = mid; else lo = mid + 1;
    }
    const int cls    = lo;
    const int ibase  = (cls == 0) ? 0 : iscan_[cls - 1];
    const int within = item - ibase;
    const int nt     = min(8, cnt_[cls] - 8 * within);

    // deterministic compaction: (half, wave, lane) order == sample order
    const bool fA = (la == cls), fB = (lb == cls);
    const unsigned long long mA = __ballot(fA);
    const unsigned long long mB = __ballot(fB);
    if (lane == 0) { wtA[wave] = __popcll(mA); wtB[wave] = __popcll(mB); }
    __syncthreads();
    int preA = 0, preB = 0, totA = 0;
#pragma unroll
    for (int w = 0; w < 8; ++w) {
        totA += wtA[w];
        if (w < wave) { preA += wtA[w]; preB += wtB[w]; }
    }
    preB += totA;
    if (fA) {
        const int r = preA + (int)__popcll(mA & ((1ull << lane) - 1)) - 8 * within;
        if (r >= 0 && r < 8) slot[r] = tid;
    }
    if (fB) {
        const int r = preB + (int)__popcll(mB & ((1ull << lane) - 1)) - 8 * within;
        if (r >= 0 && r < 8) slot[r] = tid + 512;
    }
    __syncthreads();

    panel8<true>(X, labels, sm, slot,
                 Wb + (size_t)cls * (NHID * NPC), NPC,
                 bb + (size_t)cls * NPC, nt, true, ws + WS_PB);
}

// ---------------------------------------------------------------------------
// Finalize: out[s] = pt[s] * pb[s]
// ---------------------------------------------------------------------------
__global__ void k_mul(const float* __restrict__ ws, float* __restrict__ out)
{
    const int i = blockIdx.x * 256 + threadIdx.x;
    if (i < BATCH) out[i] = ws[WS_PT + i] * ws[WS_PB + i];
}

// ---------------------------------------------------------------------------
extern "C" void kernel_launch(void* const* d_in, const int* in_sizes, int n_in,
                              void* d_out, int out_size, void* d_ws, size_t ws_size,
                              hipStream_t stream)
{
    const float* X      = (const float*)d_in[0];
    const int*   labels = (const int*)  d_in[1];
    const float* Wt     = (const float*)d_in[2];
    const float* bt     = (const float*)d_in[3];
    const float* Wb     = (const float*)d_in[4];
    const float* bb     = (const float*)d_in[5];

    hipLaunchKernelGGL(k_fused, dim3(N_TOPB + N_BOTB), dim3(512), 0, stream,
                       X, labels, Wt, bt, Wb, bb, (float*)d_ws);
    hipLaunchKernelGGL(k_mul, dim3(BATCH / 256), dim3(256), 0, stream,
                       (const float*)d_ws, (float*)d_out);
}